// Round 12
// baseline (514.251 us; speedup 1.0000x reference)
//
#include <hip/hip_runtime.h>
#include <stdint.h>
#include <math.h>

#define USER_N 100000
#define NODE_N 150000
#define DD 64
#define NNZE 2400000
#define BB 4096
#define NLV 3
#define LF 32
#define HALF_SZ 196608u  /* (3*4096*32)/2 */
#define NTILE 586        /* ceil(150000/256) */
#define NSUB 8           /* per-tile sub-segments, one per physical XCD */
#define SCAP 1024        /* capacity per (tile,xcd) segment; mean 512 */
#define EPB 4096         /* edges per scatter block */
#define LCAP 5120        /* LDS staging cap per tile (mean 4096, sigma 64) */

typedef __attribute__((ext_vector_type(8))) short bf16x8;
typedef __attribute__((ext_vector_type(4))) float f32x4;
typedef __attribute__((ext_vector_type(2))) float f32x2;

// HW_REG_XCC_ID: id=20, offset=0, width=32 -> imm = 20 | (31<<11)
#define XCC_ID_IMM 63508

// ---------------- threefry2x32 (JAX original mode) ----------------
__host__ __device__ inline void tf_block(uint32_t k0, uint32_t k1, uint32_t& x0, uint32_t& x1) {
  uint32_t ks[3] = {k0, k1, k0 ^ k1 ^ 0x1BD11BDAu};
  x0 += ks[0]; x1 += ks[1];
  const int R0[4] = {13, 15, 26, 6};
  const int R1[4] = {17, 29, 16, 24};
#pragma unroll
  for (int i = 0; i < 5; ++i) {
    const int* R = (i & 1) ? R1 : R0;
#pragma unroll
    for (int j = 0; j < 4; ++j) {
      x0 += x1;
      x1 = (x1 << R[j]) | (x1 >> (32 - R[j]));
      x1 ^= x0;
    }
    x0 += ks[(i + 1) % 3];
    x1 += ks[(i + 2) % 3] + (uint32_t)(i + 1);
  }
}

__device__ inline float tf_uniform(uint32_t ka, uint32_t kb, uint32_t m) {
  uint32_t x0, x1;
  bool first = m < HALF_SZ;
  if (first) { x0 = m; x1 = m + HALF_SZ; } else { x0 = m - HALF_SZ; x1 = m; }
  tf_block(ka, kb, x0, x1);
  uint32_t bits = first ? x0 : x1;
  return __uint_as_float((bits >> 9) | 0x3f800000u) - 1.0f;
}

// bf16 round-to-nearest-even
__device__ inline unsigned short f2bf(float x) {
  uint32_t b = __float_as_uint(x);
  return (unsigned short)((b + 0x7FFFu + ((b >> 16) & 1u)) >> 16);
}

__device__ inline float b2f(unsigned short u) {
  return __uint_as_float(((uint32_t)u) << 16);
}

// fp8 e4m3 (HW cvt, OCP on gfx950): one byte from a float
__device__ inline unsigned char f2fp8(float x) {
  return (unsigned char)(__builtin_amdgcn_cvt_pk_fp8_f32(x, x, 0, false) & 0xFF);
}

// decode 4 packed e4m3 bytes -> 4 floats, then acc += v * row4
__device__ inline void fp8_fma(float4& acc, uint2 rec, uint32_t wrd) {
  float vv = __uint_as_float(rec.y);
  f32x2 lo = __builtin_amdgcn_cvt_pk_f32_fp8((int)wrd, false);
  f32x2 hi = __builtin_amdgcn_cvt_pk_f32_fp8((int)wrd, true);
  acc.x = fmaf(vv, lo.x, acc.x);
  acc.y = fmaf(vv, lo.y, acc.y);
  acc.z = fmaf(vv, hi.x, acc.z);
  acc.w = fmaf(vv, hi.y, acc.w);
}

// ---------------- kernels ----------------
// init (r21): fp8-mirror init (blocks < 9375) + encoder weight prep + transform
// weight prep (9375..10111) + cursor/cl zeroing (10111..10405).
// twt layout (per matrix, per layer): elem e -> j=e&7, quad=(e>>3)&3, h=(e>>5)&1,
// n=(e>>6)&15, c=e>>10; src k = h*32+quad*8+j; val = W[l*4096 + k*64 + c*16 + n].
__global__ __launch_bounds__(256) void k_init(
    const float* __restrict__ ego, uint32_t* __restrict__ E8,
    const float* __restrict__ uh_w, const float* __restrict__ ud_w1,
    const float* __restrict__ ud_w2, const float* __restrict__ ih_w,
    const float* __restrict__ id_w1, const float* __restrict__ id_w2,
    const float* __restrict__ gc_w, const float* __restrict__ bi_w,
    unsigned short* __restrict__ s1t, unsigned short* __restrict__ s2t,
    unsigned short* __restrict__ s3t, unsigned short* __restrict__ twt,
    int* __restrict__ cursor, float* __restrict__ clbuf) {
  if (blockIdx.x >= 10111) {
    int i = (blockIdx.x - 10111) * 256 + threadIdx.x;
    if (i < NTILE * NSUB * 16) cursor[i] = 0;
    if (i == 0) { clbuf[0] = 0.f; ((int*)clbuf)[1] = 0; }
    return;
  }
  if (blockIdx.x < 9375) {
    int i = blockIdx.x * 256 + threadIdx.x;  // float4 index
    float4 v = ((const float4*)ego)[i];
    int w01 = __builtin_amdgcn_cvt_pk_fp8_f32(v.x, v.y, 0, false);
    int w = __builtin_amdgcn_cvt_pk_fp8_f32(v.z, v.w, w01, true);
    E8[i] = (uint32_t)w;
    return;
  }
  int i = (blockIdx.x - 9375) * 256 + threadIdx.x;
  if (i < 24576) {                     // s1t[sl][e<64][d<64]
    int sl = i >> 12, r = i & 4095, e = r >> 6, d = r & 63;
    const float* src = (sl >= 3 ? ih_w : uh_w);
    int l = sl % 3;
    s1t[i] = f2bf(src[l * 4096 + d * 64 + e]);
  } else if (i < 24576 + 98304) {      // s2t[sl][e<256][d<64]
    int j = i - 24576;
    int sl = j >> 14, r = j & 16383, e = r >> 6, d = r & 63;
    const float* src = (sl >= 3 ? id_w1 : ud_w1);
    int l = sl % 3;
    s2t[j] = f2bf(src[l * 16384 + d * 256 + e]);
  } else if (i < 172032) {             // s3t[sl][e<32][d<256]
    int j = i - 24576 - 98304;
    int sl = j >> 13, r = j & 8191, e = r >> 8, d = r & 255;
    const float* src = (sl >= 3 ? id_w2 : ud_w2);
    int l = sl % 3;
    s3t[j] = f2bf(src[l * 8192 + d * 32 + e]);
  } else if (i < 172032 + 16384) {     // twt[m<2][l<2][e<4096]
    int j = i - 172032;
    int m = j >> 13;
    int rest = j & 8191;
    int l = rest >> 12;
    int e = rest & 4095;
    int jj = e & 7, quad = (e >> 3) & 3, h = (e >> 5) & 1;
    int n = (e >> 6) & 15, c = e >> 10;
    int k = h * 32 + quad * 8 + jj;
    const float* src = m ? bi_w : gc_w;
    twt[j] = f2bf(src[l * 4096 + k * 64 + c * 16 + n]);
  }
}

// Scatter v2 (r18): in-block counting sort over 586 tiles + LDS-staged
// writeout (bin-grouped bursts instead of 2.4M scattered 8B writes).
__global__ __launch_bounds__(256) void k_scatter_t(const int* __restrict__ rows,
                                                   const int* __restrict__ cols,
                                                   const float* __restrict__ vals,
                                                   int* __restrict__ cursor,
                                                   uint2* __restrict__ sedge_r) {
  __shared__ int cnt[NTILE];
  __shared__ int binbase[NTILE];
  __shared__ int gbase[NTILE];
  __shared__ int partial[256];
  __shared__ uint2 staged[EPB];            // 32KB
  __shared__ unsigned short tileof[EPB];   // 8KB
  int t = threadIdx.x;
  for (int i = t; i < NTILE; i += 256) cnt[i] = 0;
  __syncthreads();
  int ebase = blockIdx.x * EPB;
  int r[16], rk[16];
#pragma unroll
  for (int j = 0; j < 16; ++j) {
    int e = ebase + j * 256 + t;
    r[j] = (e < NNZE) ? rows[e] : -1;
    rk[j] = (r[j] >= 0) ? atomicAdd(&cnt[r[j] >> 8], 1) : 0;
  }
  __syncthreads();
  // scan over 586 bins: thread t owns bins [3t, 3t+own)
  int b0 = t * 3;
  int own = (b0 < NTILE) ? ((NTILE - b0 < 3) ? (NTILE - b0) : 3) : 0;
  int s0 = 0;
  for (int k = 0; k < own; ++k) s0 += cnt[b0 + k];
  partial[t] = s0;
  __syncthreads();
  for (int off = 1; off < 256; off <<= 1) {
    int add = (t >= off) ? partial[t - off] : 0;
    __syncthreads();
    partial[t] += add;
    __syncthreads();
  }
  int excl = partial[t] - s0;
  unsigned myx = __builtin_amdgcn_s_getreg(XCC_ID_IMM) & (NSUB - 1);
  {
    int run = excl;
    for (int k = 0; k < own; ++k) {
      int b = b0 + k;
      int c = cnt[b];
      binbase[b] = run;
      gbase[b] = c ? atomicAdd(&cursor[(b * NSUB + (int)myx) * 16], c) : 0;
      run += c;
    }
  }
  __syncthreads();
  // stage records bin-grouped
#pragma unroll
  for (int j = 0; j < 16; ++j) {
    if (r[j] < 0) continue;
    int e = ebase + j * 256 + t;
    int tile = r[j] >> 8;
    int pos = binbase[tile] + rk[j];
    staged[pos] = make_uint2((uint32_t)cols[e] | ((uint32_t)(r[j] & 255) << 18),
                             __float_as_uint(vals[e]));
    tileof[pos] = (unsigned short)tile;
  }
  __syncthreads();
  // writeout: staged order is bin-grouped -> bursts per tile range
  int nrec = NNZE - ebase;
  if (nrec > EPB) nrec = EPB;
  for (int i = t; i < nrec; i += 256) {
    int tile = tileof[i];
    int q = i - binbase[tile];
    int p = gbase[tile] + q;
    uint2 rec = staged[i];
    if (p < SCAP) {
      sedge_r[(size_t)(tile * NSUB + (int)myx) * SCAP + p] = rec;
    } else {
#pragma unroll 1
      for (int att = 1; att < NSUB; ++att) {
        int seg = tile * NSUB + (int)((myx + att) & (NSUB - 1));
        int p2 = atomicAdd(&cursor[seg * 16], 1);
        if (p2 < SCAP) { sedge_r[(size_t)seg * SCAP + p2] = rec; break; }
      }
    }
  }
}

// per-tile 256-bin counting sort (r16): folded scan + LDS-staged coalesced
// writeout.
__global__ __launch_bounds__(256) void k_sort_t(const uint2* __restrict__ sedge_r,
                                                const int* __restrict__ cursor,
                                                uint2* __restrict__ sedge,
                                                int* __restrict__ row_start) {
  __shared__ int hist[256], buf[256], curs[256];
  __shared__ int obase_s;
  __shared__ uint2 staged[LCAP];   // 40KB
  int t = threadIdx.x;
  int tile = blockIdx.x;
  if (t == 0) obase_s = 0;
  hist[t] = 0;
  __syncthreads();
  // folded scan: obase = sum of totals over tiles < tile (L2-resident reads)
  int ob = 0;
  for (int i = t; i < tile * NSUB; i += 256) {
    int c = cursor[i * 16];
    ob += (c < SCAP) ? c : SCAP;
  }
  if (ob) atomicAdd(&obase_s, ob);
  // histogram over this tile's 8 segments
  int segcnt[NSUB];
#pragma unroll
  for (int x = 0; x < NSUB; ++x) {
    int c = cursor[(tile * NSUB + x) * 16];
    segcnt[x] = (c < SCAP) ? c : SCAP;
  }
#pragma unroll 1
  for (int x = 0; x < NSUB; ++x) {
    const uint2* sp = sedge_r + (size_t)(tile * NSUB + x) * SCAP;
    for (int i = t; i < segcnt[x]; i += 256)
      atomicAdd(&hist[sp[i].x >> 18], 1);
  }
  __syncthreads();
  int obase = obase_s;
  int v = hist[t];
  buf[t] = v;
  __syncthreads();
  for (int off = 1; off < 256; off <<= 1) {
    int add = (t >= off) ? buf[t - off] : 0;
    __syncthreads();
    buf[t] += add;
    __syncthreads();
  }
  int total = buf[255];
  int excl = buf[t] - v;
  curs[t] = excl;
  int row = tile * 256 + t;
  if (row < NODE_N) row_start[row] = obase + excl;
  if (tile == NTILE - 1 && t == 0) row_start[NODE_N] = NNZE;
  __syncthreads();
#pragma unroll 1
  for (int x = 0; x < NSUB; ++x) {
    const uint2* sp = sedge_r + (size_t)(tile * NSUB + x) * SCAP;
    for (int i = t; i < segcnt[x]; i += 256) {
      uint2 rec = sp[i];
      int rl = rec.x >> 18;
      int p = atomicAdd(&curs[rl], 1);
      uint2 outrec = make_uint2(rec.x & 0x3FFFFu, rec.y);
      if (p < LCAP) staged[p] = outrec;
      else sedge[obase + p] = outrec;   // 16-sigma fallback
    }
  }
  __syncthreads();
  int n = (total < LCAP) ? total : LCAP;
  for (int i = t; i < n; i += 256)
    sedge[obase + i] = staged[i];
}

// Fused SpMM+transform v2 (r22): Eout now bf16 (halves the write, its only
// consumer re-rounds to bf16 anyway; added err ~2e-4 << existing fp8 err),
// weight fragments prefetched BEFORE phase 1 (latency hides under gather),
// phase-1 epilogue uses packed ushort4 LDS stores (was 600K bank conflicts).
__global__ __launch_bounds__(256) void k_spmmt(const uint32_t* __restrict__ E8in,
                                               const uint2* __restrict__ sedge,
                                               const int* __restrict__ row_start,
                                               const unsigned short* __restrict__ gwt,
                                               const float* __restrict__ gb,
                                               const unsigned short* __restrict__ bwt,
                                               const float* __restrict__ bb,
                                               unsigned short* __restrict__ Eout,
                                               unsigned char* __restrict__ E8out) {
  __shared__ unsigned short sS[16][72];   // side tile bf16 (pad 72)
  __shared__ unsigned short sP[16][72];   // E.side tile
  __shared__ float sqp[4][16];            // per-wave partial l2 sums
  int t = threadIdx.x;
  int wv = t >> 6, lane = t & 63;
  int n = lane & 15, quad = lane >> 4;
  int i0 = blockIdx.x * 16;
  // prefetch phase-2 operands (latency hides under the gather loop)
  bf16x8 wg0 = *(const bf16x8*)&gwt[((size_t)(wv * 16 + n) * 2 + 0) * 32 + quad * 8];
  bf16x8 wg1 = *(const bf16x8*)&gwt[((size_t)(wv * 16 + n) * 2 + 1) * 32 + quad * 8];
  bf16x8 wb0 = *(const bf16x8*)&bwt[((size_t)(wv * 16 + n) * 2 + 0) * 32 + quad * 8];
  bf16x8 wb1 = *(const bf16x8*)&bwt[((size_t)(wv * 16 + n) * 2 + 1) * 32 + quad * 8];
  float gbl = gb[wv * 16 + n];
  float bbl = bb[wv * 16 + n];
  // ---- phase 1: spmm, wave wv handles rows i0+wv*4 .. +3 ----
  {
    int g = lane >> 4;
    int q = lane & 15;
#pragma unroll 1
    for (int rr = 0; rr < 4; ++rr) {
      int r = i0 + wv * 4 + rr;
      int rs = row_start[r], re = row_start[r + 1];
      float4 acc = make_float4(0.f, 0.f, 0.f, 0.f);
      int e = rs;
      for (; e + 16 <= re; e += 16) {
        uint2 e0 = sedge[e + g];
        uint2 e1 = sedge[e + 4 + g];
        uint2 e2 = sedge[e + 8 + g];
        uint2 e3 = sedge[e + 12 + g];
        uint32_t a0 = E8in[(size_t)e0.x * 16 + q];
        uint32_t a1 = E8in[(size_t)e1.x * 16 + q];
        uint32_t a2 = E8in[(size_t)e2.x * 16 + q];
        uint32_t a3 = E8in[(size_t)e3.x * 16 + q];
        fp8_fma(acc, e0, a0);
        fp8_fma(acc, e1, a1);
        fp8_fma(acc, e2, a2);
        fp8_fma(acc, e3, a3);
      }
      for (; e + 8 <= re; e += 8) {
        uint2 e0 = sedge[e + g];
        uint2 e1 = sedge[e + 4 + g];
        uint32_t a0 = E8in[(size_t)e0.x * 16 + q];
        uint32_t a1 = E8in[(size_t)e1.x * 16 + q];
        fp8_fma(acc, e0, a0);
        fp8_fma(acc, e1, a1);
      }
      for (; e + 4 <= re; e += 4) {
        uint2 e0 = sedge[e + g];
        uint32_t a0 = E8in[(size_t)e0.x * 16 + q];
        fp8_fma(acc, e0, a0);
      }
      for (; e < re; ++e) {
        if (g == (e & 3)) {
          uint2 e0 = sedge[e];
          uint32_t a0 = E8in[(size_t)e0.x * 16 + q];
          fp8_fma(acc, e0, a0);
        }
      }
#pragma unroll
      for (int off = 16; off <= 32; off <<= 1) {
        acc.x += __shfl_xor(acc.x, off, 64);
        acc.y += __shfl_xor(acc.y, off, 64);
        acc.z += __shfl_xor(acc.z, off, 64);
        acc.w += __shfl_xor(acc.w, off, 64);
      }
      if (g == 0) {
        uint32_t ew = E8in[(size_t)r * 16 + q];
        f32x2 elo = __builtin_amdgcn_cvt_pk_f32_fp8((int)ew, false);
        f32x2 ehi = __builtin_amdgcn_cvt_pk_f32_fp8((int)ew, true);
        int lr = wv * 4 + rr;
        ushort4 vs, vp;
        vs.x = f2bf(acc.x); vs.y = f2bf(acc.y);
        vs.z = f2bf(acc.z); vs.w = f2bf(acc.w);
        vp.x = f2bf(acc.x * elo.x); vp.y = f2bf(acc.y * elo.y);
        vp.z = f2bf(acc.z * ehi.x); vp.w = f2bf(acc.w * ehi.y);
        *(ushort4*)&sS[lr][q * 4] = vs;
        *(ushort4*)&sP[lr][q * 4] = vp;
      }
    }
  }
  __syncthreads();
  // ---- phase 2: transform; wave wv = output colblock c ----
  const f32x4 z = {0.f, 0.f, 0.f, 0.f};
  bf16x8 as0 = *(const bf16x8*)&sS[n][quad * 8];
  bf16x8 as1 = *(const bf16x8*)&sS[n][32 + quad * 8];
  bf16x8 ap0 = *(const bf16x8*)&sP[n][quad * 8];
  bf16x8 ap1 = *(const bf16x8*)&sP[n][32 + quad * 8];
  f32x4 ag = __builtin_amdgcn_mfma_f32_16x16x32_bf16(as0, wg0, z, 0, 0, 0);
  ag = __builtin_amdgcn_mfma_f32_16x16x32_bf16(as1, wg1, ag, 0, 0, 0);
  f32x4 ab = __builtin_amdgcn_mfma_f32_16x16x32_bf16(ap0, wb0, z, 0, 0, 0);
  ab = __builtin_amdgcn_mfma_f32_16x16x32_bf16(ap1, wb1, ab, 0, 0, 0);
  float v[4];
  float sq[4];
#pragma unroll
  for (int r = 0; r < 4; ++r) {
    float a1 = ag[r] + gbl;
    a1 = (a1 > 0.f) ? a1 : 0.01f * a1;
    float a2 = ab[r] + bbl;
    a2 = (a2 > 0.f) ? a2 : 0.01f * a2;
    float vv = a1 + a2;
    v[r] = vv;
    sq[r] = vv * vv;
  }
#pragma unroll
  for (int off = 1; off < 16; off <<= 1) {
    sq[0] += __shfl_xor(sq[0], off, 64);
    sq[1] += __shfl_xor(sq[1], off, 64);
    sq[2] += __shfl_xor(sq[2], off, 64);
    sq[3] += __shfl_xor(sq[3], off, 64);
  }
  if (n == 0) {
#pragma unroll
    for (int r = 0; r < 4; ++r) sqp[wv][quad * 4 + r] = sq[r];
  }
  __syncthreads();
#pragma unroll
  for (int r = 0; r < 4; ++r) {
    int row = quad * 4 + r;
    float tot = sqp[0][row] + sqp[1][row] + sqp[2][row] + sqp[3][row];
    float inv = 1.f / fmaxf(sqrtf(tot), 1e-12f);
    float vn = v[r] * inv;
    size_t o = (size_t)(i0 + row) * DD + wv * 16 + n;
    Eout[o] = f2bf(vn);
    E8out[o] = f2fp8(vn);
  }
}

// Encoder v7 (r22): E1/E2 consumed as bf16 (converted to fp32 before the sum;
// ego stays fp32). Otherwise identical to the verified v6.
__global__ __launch_bounds__(256) void k_encoder6(
    const float* __restrict__ ego, const unsigned short* __restrict__ E1,
    const unsigned short* __restrict__ E2, const int* __restrict__ uid,
    const int* __restrict__ iid,
    const unsigned short* __restrict__ s1t, const unsigned short* __restrict__ s2t,
    const unsigned short* __restrict__ s3t,
    const float* __restrict__ uh_b, const float* __restrict__ ud_b1,
    const float* __restrict__ ud_b2, const float* __restrict__ ih_b,
    const float* __restrict__ id_b1, const float* __restrict__ id_b2,
    float* __restrict__ recs_u, float* __restrict__ recs_i) {
  __shared__ unsigned short X[32][72];    // 4.6KB (pad 72: conflict-free)
  __shared__ unsigned short R1[32][64];   // 4KB
  __shared__ unsigned short T[32][256];   // 16KB
  int t = threadIdx.x;
  int w = t >> 6, lane = t & 63;
  int n = lane & 15, quad = lane >> 4;
  int trow = w & 1;      // which 16-row tile
  int cg = w >> 1;       // column-group half
  int r0 = blockIdx.x * 32;
  int l = blockIdx.y, side = blockIdx.z;
  int sl = side * 3 + l;
  const float* hb = side ? ih_b : uh_b;
  const float* bb1 = side ? id_b1 : ud_b1;
  const float* bb2 = side ? id_b2 : ud_b2;
  float* recs = side ? recs_i : recs_u;
  const f32x4 z = {0.f, 0.f, 0.f, 0.f};

  {  // gather 32 rows: X = bf16(ego + E1 + E2) at uid/iid rows (E1/E2 bf16)
    int row = t >> 3;
    int c0 = (t & 7) * 8;
    int node = side ? (USER_N + iid[r0 + row]) : uid[r0 + row];
    const float* pe = ego + (size_t)node * 64 + c0;
    bf16x8 v1 = *(const bf16x8*)(E1 + (size_t)node * 64 + c0);
    bf16x8 v2 = *(const bf16x8*)(E2 + (size_t)node * 64 + c0);
#pragma unroll
    for (int j = 0; j < 8; ++j)
      X[row][c0 + j] = f2bf(pe[j] + b2f((unsigned short)v1[j]) +
                            b2f((unsigned short)v2[j]));
  }
  __syncthreads();

  {  // stage1: R1 = tanh(X @ W0 + b0). 16x64 out per tile; wave: 2 colblocks.
    bf16x8 a0 = *(const bf16x8*)&X[trow * 16 + n][quad * 8];
    bf16x8 a1 = *(const bf16x8*)&X[trow * 16 + n][32 + quad * 8];
    const unsigned short* Wt = s1t + (size_t)sl * 4096;  // [e=64][d=64]
#pragma unroll
    for (int cc = 0; cc < 2; ++cc) {
      int cb = cg * 2 + cc;
      bf16x8 wb0 = *(const bf16x8*)&Wt[(size_t)(cb * 16 + n) * 64 + quad * 8];
      bf16x8 wb1 = *(const bf16x8*)&Wt[(size_t)(cb * 16 + n) * 64 + 32 + quad * 8];
      f32x4 acc = __builtin_amdgcn_mfma_f32_16x16x32_bf16(a0, wb0, z, 0, 0, 0);
      acc = __builtin_amdgcn_mfma_f32_16x16x32_bf16(a1, wb1, acc, 0, 0, 0);
      float bias = hb[l * 64 + cb * 16 + n];
#pragma unroll
      for (int r = 0; r < 4; ++r)
        R1[trow * 16 + quad * 4 + r][cb * 16 + n] = f2bf(tanhf(acc[r] + bias));
    }
  }
  __syncthreads();

  {  // stage2: T = tanh(R1 @ W1 + b1). 16x256 per tile; wave: 8 colblocks.
    bf16x8 a0 = *(const bf16x8*)&R1[trow * 16 + n][quad * 8];
    bf16x8 a1 = *(const bf16x8*)&R1[trow * 16 + n][32 + quad * 8];
    const unsigned short* Wt = s2t + (size_t)sl * 16384;  // [e=256][d=64]
#pragma unroll
    for (int cc = 0; cc < 8; ++cc) {
      int cb = cg * 8 + cc;
      bf16x8 wb0 = *(const bf16x8*)&Wt[(size_t)(cb * 16 + n) * 64 + quad * 8];
      bf16x8 wb1 = *(const bf16x8*)&Wt[(size_t)(cb * 16 + n) * 64 + 32 + quad * 8];
      f32x4 acc = __builtin_amdgcn_mfma_f32_16x16x32_bf16(a0, wb0, z, 0, 0, 0);
      acc = __builtin_amdgcn_mfma_f32_16x16x32_bf16(a1, wb1, acc, 0, 0, 0);
      float bias = bb1[l * 256 + cb * 16 + n];
#pragma unroll
      for (int r = 0; r < 4; ++r)
        T[trow * 16 + quad * 4 + r][cb * 16 + n] = f2bf(tanhf(acc[r] + bias));
    }
  }
  __syncthreads();

  {  // stage3: recs = T @ W2 + b2. K=256 chained; wave: 1 colblock (cg).
    const unsigned short* Wt = s3t + (size_t)sl * 8192;  // [e=32][d=256]
    f32x4 acc = z;
#pragma unroll
    for (int h = 0; h < 8; ++h) {
      bf16x8 a = *(const bf16x8*)&T[trow * 16 + n][h * 32 + quad * 8];
      bf16x8 b = *(const bf16x8*)&Wt[(size_t)(cg * 16 + n) * 256 + h * 32 + quad * 8];
      acc = __builtin_amdgcn_mfma_f32_16x16x32_bf16(a, b, acc, 0, 0, 0);
    }
    float bias = bb2[l * 32 + cg * 16 + n];
#pragma unroll
    for (int r = 0; r < 4; ++r)
      recs[((size_t)l * BB + (r0 + trow * 16 + quad * 4 + r)) * 32 + cg * 16 + n] =
          acc[r] + bias;
  }
}

// attn+noise fused (r19): noise consumes exactly the att values attn computes
// per-lane (s<->l, d<->k). Threefry mapping identical to the original k_noise.
__global__ __launch_bounds__(256) void k_attnz(const float* __restrict__ recs_u,
                                               const float* __restrict__ recs_i,
                                               const float* __restrict__ qw, const float* __restrict__ qb,
                                               const float* __restrict__ kw, const float* __restrict__ kb,
                                               const float* __restrict__ vw, const float* __restrict__ vb,
                                               uint32_t ku0, uint32_t ku1, uint32_t ki0, uint32_t ki1,
                                               float* __restrict__ att_u, float* __restrict__ att_i,
                                               unsigned short* __restrict__ n1b,
                                               unsigned short* __restrict__ n2b,
                                               float* __restrict__ posdot) {
  int side = blockIdx.y;
  const float* recs = side ? recs_i : recs_u;
  float* att = side ? att_i : att_u;
  uint32_t ka = side ? ki0 : ku0;
  uint32_t kb2 = side ? ki1 : ku1;
  int t = threadIdx.x;
  int b = blockIdx.x * 8 + (t >> 5);
  int d = t & 31;
  float x0 = recs[((size_t)0 * BB + b) * 32 + d];
  float x1 = recs[((size_t)1 * BB + b) * 32 + d];
  float x2 = recs[((size_t)2 * BB + b) * 32 + d];
  float q0 = qb[d], q1 = q0, q2 = q0;
  float c0 = kb[d], c1 = c0, c2 = c0;
  float v0 = vb[d], v1 = v0, v2 = v0;
#pragma unroll 4
  for (int kk = 0; kk < 32; ++kk) {
    float xa = __shfl(x0, kk, 32);
    float xb = __shfl(x1, kk, 32);
    float xc = __shfl(x2, kk, 32);
    float wq = qw[kk * 32 + d], wk = kw[kk * 32 + d], wv = vw[kk * 32 + d];
    q0 += xa * wq; q1 += xb * wq; q2 += xc * wq;
    c0 += xa * wk; c1 += xb * wk; c2 += xc * wk;
    v0 += xa * wv; v1 += xb * wv; v2 += xc * wv;
  }
  float qs[3] = {q0, q1, q2}, ks[3] = {c0, c1, c2}, vs[3] = {v0, v1, v2};
  float sc[3][3];
#pragma unroll
  for (int s = 0; s < 3; ++s)
#pragma unroll
    for (int u = 0; u < 3; ++u) {
      float p = qs[s] * ks[u];
#pragma unroll
      for (int off = 16; off; off >>= 1) p += __shfl_xor(p, off, 32);
      sc[s][u] = p * 0.17677669529663687f;  // 1/sqrt(32)
    }
#pragma unroll
  for (int s = 0; s < 3; ++s) {
    float m = fmaxf(sc[s][0], fmaxf(sc[s][1], sc[s][2]));
    float e0 = __expf(sc[s][0] - m), e1 = __expf(sc[s][1] - m), e2 = __expf(sc[s][2] - m);
    float inv = 1.f / (e0 + e1 + e2);
    float r = (e0 * vs[0] + e1 * vs[1] + e2 * vs[2]) * inv;
    att[(size_t)b * 96 + s * 32 + d] = r;
    // ---- noise (was k_noise) ----
    float ss = r * r;
#pragma unroll
    for (int off = 16; off; off >>= 1) ss += __shfl_xor(ss, off, 32);
    float nv1 = r / fmaxf(sqrtf(ss), 1e-12f);
    uint32_t mm = ((uint32_t)(s * BB + b)) * 32u + (uint32_t)d;
    float u = tf_uniform(ka, kb2, mm);
    float us = u * u;
#pragma unroll
    for (int off = 16; off; off >>= 1) us += __shfl_xor(us, off, 32);
    float un = u / fmaxf(sqrtf(us), 1e-12f);
    float sgn = (r > 0.f) ? 1.f : ((r < 0.f) ? -1.f : 0.f);
    float rn = r + sgn * un * 0.1f;
    float s2 = rn * rn;
#pragma unroll
    for (int off = 16; off; off >>= 1) s2 += __shfl_xor(s2, off, 32);
    float nv2 = rn / fmaxf(sqrtf(s2), 1e-12f);
    float pd = nv1 * nv2;
#pragma unroll
    for (int off = 16; off; off >>= 1) pd += __shfl_xor(pd, off, 32);
    int g = side * (NLV * BB) + s * BB + b;
    size_t o = (size_t)g * 32 + d;
    n1b[o] = f2bf(nv1);
    n2b[o] = f2bf(nv2);
    if (d == 0) posdot[g] = pd;
  }
}

// ttl via MFMA + clred FOLDED IN (r19): block-reduce log(ttl)-5*posdot, one
// atomicAdd per block; last block (counter) writes the final cl output.
__global__ __launch_bounds__(256) void k_ttl(const unsigned short* __restrict__ n1b,
                                             const unsigned short* __restrict__ n2b,
                                             const float* __restrict__ posdot,
                                             float* __restrict__ clbuf,
                                             float* __restrict__ outp) {
  __shared__ float ws[4];
  int t = threadIdx.x;
  int wv = t >> 6, lane = t & 63;
  int sl = blockIdx.x >> 6;            // 6 slices
  int istripe = blockIdx.x & 63;       // 64 stripes of 64 rows
  int i0 = istripe * 64 + wv * 16;
  const unsigned short* ab = n1b + (size_t)sl * BB * 32;
  const unsigned short* bb = n2b + (size_t)sl * BB * 32;
  int m = lane & 15, quad = lane >> 4;
  bf16x8 afrag = *(const bf16x8*)&ab[(size_t)(i0 + m) * 32 + quad * 8];
  float r0a = 0.f, r1a = 0.f, r2a = 0.f, r3a = 0.f;
  f32x4 z = {0.f, 0.f, 0.f, 0.f};
  for (int jt = 0; jt < 256; jt += 4) {
    bf16x8 b0 = *(const bf16x8*)&bb[((size_t)((jt + 0) * 16 + m)) * 32 + quad * 8];
    bf16x8 b1 = *(const bf16x8*)&bb[((size_t)((jt + 1) * 16 + m)) * 32 + quad * 8];
    bf16x8 b2 = *(const bf16x8*)&bb[((size_t)((jt + 2) * 16 + m)) * 32 + quad * 8];
    bf16x8 b3 = *(const bf16x8*)&bb[((size_t)((jt + 3) * 16 + m)) * 32 + quad * 8];
    f32x4 s0 = __builtin_amdgcn_mfma_f32_16x16x32_bf16(afrag, b0, z, 0, 0, 0);
    f32x4 s1 = __builtin_amdgcn_mfma_f32_16x16x32_bf16(afrag, b1, z, 0, 0, 0);
    f32x4 s2 = __builtin_amdgcn_mfma_f32_16x16x32_bf16(afrag, b2, z, 0, 0, 0);
    f32x4 s3 = __builtin_amdgcn_mfma_f32_16x16x32_bf16(afrag, b3, z, 0, 0, 0);
    r0a += __expf(s0.x * 5.f) + __expf(s1.x * 5.f) + __expf(s2.x * 5.f) + __expf(s3.x * 5.f);
    r1a += __expf(s0.y * 5.f) + __expf(s1.y * 5.f) + __expf(s2.y * 5.f) + __expf(s3.y * 5.f);
    r2a += __expf(s0.z * 5.f) + __expf(s1.z * 5.f) + __expf(s2.z * 5.f) + __expf(s3.z * 5.f);
    r3a += __expf(s0.w * 5.f) + __expf(s1.w * 5.f) + __expf(s2.w * 5.f) + __expf(s3.w * 5.f);
  }
#pragma unroll
  for (int off = 1; off < 16; off <<= 1) {
    r0a += __shfl_xor(r0a, off, 64);
    r1a += __shfl_xor(r1a, off, 64);
    r2a += __shfl_xor(r2a, off, 64);
    r3a += __shfl_xor(r3a, off, 64);
  }
  float part = 0.f;
  if (m == 0) {
    int rbase = sl * BB + i0 + quad * 4;
    part = (logf(r0a) - posdot[rbase + 0] * 5.0f)
         + (logf(r1a) - posdot[rbase + 1] * 5.0f)
         + (logf(r2a) - posdot[rbase + 2] * 5.0f)
         + (logf(r3a) - posdot[rbase + 3] * 5.0f);
  }
#pragma unroll
  for (int off = 1; off < 64; off <<= 1)
    part += __shfl_xor(part, off, 64);
  if (lane == 0) ws[wv] = part;
  __syncthreads();
  if (t == 0) {
    float blk = ws[0] + ws[1] + ws[2] + ws[3];
    atomicAdd(&clbuf[0], blk);
    __threadfence();
    int done = atomicAdd((int*)&clbuf[1], 1);
    if (done == 383) {
      float total = atomicAdd(&clbuf[0], 0.0f);
      outp[2 * BB] = total * (1.f / 12288.f);
    }
  }
}

__global__ __launch_bounds__(256) void k_head(const float* __restrict__ att_u,
                                              const float* __restrict__ att_i,
                                              const float* __restrict__ skills,
                                              const float* __restrict__ w1, const float* __restrict__ b1,
                                              const float* __restrict__ w2, const float* __restrict__ b2,
                                              const float* __restrict__ pw, const float* __restrict__ pb,
                                              float* __restrict__ outp) {
  __shared__ float diag[4][96], t1[4][64];
  int t = threadIdx.x;
  int w = t >> 6, lane = t & 63;
  int b = blockIdx.x * 4 + w;
  for (int j = lane; j < 96; j += 64) {
    float su = 1.f / (1.f + __expf(-att_u[(size_t)b * 96 + j]));
    float si = 1.f / (1.f + __expf(-att_i[(size_t)b * 96 + j]));
    diag[w][j] = (su - si) * skills[(size_t)b * 96 + j];
  }
  __syncthreads();
  float a = b1[lane];
#pragma unroll 8
  for (int j = 0; j < 96; ++j) a += diag[w][j] * w1[j * 64 + lane];
  t1[w][lane] = tanhf(a);
  __syncthreads();
  float h = b2[lane];
#pragma unroll 8
  for (int kk = 0; kk < 64; ++kk) h += t1[w][kk] * w2[kk * 64 + lane];
  float p0 = h * pw[lane * 2 + 0];
  float p1 = h * pw[lane * 2 + 1];
#pragma unroll
  for (int off = 32; off; off >>= 1) {
    p0 += __shfl_xor(p0, off, 64);
    p1 += __shfl_xor(p1, off, 64);
  }
  if (lane == 0) {
    float l0 = p0 + pb[0], l1 = p1 + pb[1];
    float m = fmaxf(l0, l1);
    float e0 = __expf(l0 - m), e1 = __expf(l1 - m);
    float inv = 1.f / (e0 + e1);
    outp[(size_t)b * 2 + 0] = e0 * inv;
    outp[(size_t)b * 2 + 1] = e1 * inv;
  }
}

// ---------------- launcher ----------------
extern "C" void kernel_launch(void* const* d_in, const int* in_sizes, int n_in,
                              void* d_out, int out_size, void* d_ws, size_t ws_size,
                              hipStream_t stream) {
  const float* ego    = (const float*)d_in[0];
  const float* gc_w   = (const float*)d_in[1];
  const float* gc_b   = (const float*)d_in[2];
  const float* bi_w   = (const float*)d_in[3];
  const float* bi_b   = (const float*)d_in[4];
  const float* uh_w   = (const float*)d_in[5];
  const float* uh_b   = (const float*)d_in[6];
  const float* ih_w   = (const float*)d_in[7];
  const float* ih_b   = (const float*)d_in[8];
  const float* ud_w1  = (const float*)d_in[9];
  const float* ud_b1  = (const float*)d_in[10];
  const float* ud_w2  = (const float*)d_in[11];
  const float* ud_b2  = (const float*)d_in[12];
  const float* id_w1  = (const float*)d_in[13];
  const float* id_b1  = (const float*)d_in[14];
  const float* id_w2  = (const float*)d_in[15];
  const float* id_b2  = (const float*)d_in[16];
  const float* q_w    = (const float*)d_in[17];
  const float* q_b    = (const float*)d_in[18];
  const float* k_w    = (const float*)d_in[19];
  const float* k_b    = (const float*)d_in[20];
  const float* v_w    = (const float*)d_in[21];
  const float* v_b    = (const float*)d_in[22];
  const float* dg_w1  = (const float*)d_in[23];
  const float* dg_b1  = (const float*)d_in[24];
  const float* dg_w2  = (const float*)d_in[25];
  const float* dg_b2  = (const float*)d_in[26];
  const float* pr_w   = (const float*)d_in[27];
  const float* pr_b   = (const float*)d_in[28];
  const float* adj_vals = (const float*)d_in[29];
  const float* skills = (const float*)d_in[30];
  const int* user_id  = (const int*)d_in[31];
  const int* item_id  = (const int*)d_in[32];
  const int* adj_rows = (const int*)d_in[33];
  const int* adj_cols = (const int*)d_in[34];
  float* outp = (float*)d_out;

  char* w = (char*)d_ws;
  auto alloc = [&](size_t bytes) -> char* {
    char* p = w;
    w += (bytes + 255) & ~(size_t)255;
    return p;
  };
  unsigned short* E1 = (unsigned short*)alloc((size_t)NODE_N * DD * 2);  // bf16
  unsigned short* E2 = (unsigned short*)alloc((size_t)NODE_N * DD * 2);  // bf16
  uint32_t* E8a = (uint32_t*)alloc((size_t)NODE_N * DD);   // fp8 mirror A, 9.6MB
  uint32_t* E8b = (uint32_t*)alloc((size_t)NODE_N * DD);   // fp8 mirror B, 9.6MB
  uint2* sedge_r= (uint2*)alloc((size_t)NTILE * NSUB * SCAP * 8);  // dead after sort
  uint2* sedge  = (uint2*)alloc((size_t)NNZE * 8);   // row-sorted CSR
  int*   cursor = (int*)  alloc((size_t)NTILE * NSUB * 16 * 4);
  int*   row_start = (int*)alloc((size_t)(NODE_N + 1) * 4);
  float* posdot = (float*)alloc((size_t)6 * BB * 4);
  float* clbuf  = (float*)alloc(256);                  // [0]=acc, [1]=cnt
  unsigned short* s1t = (unsigned short*)alloc((size_t)24576 * 2);   // enc W0^T bf16
  unsigned short* s2t = (unsigned short*)alloc((size_t)98304 * 2);   // enc W1^T bf16
  unsigned short* s3t = (unsigned short*)alloc((size_t)49152 * 2);   // enc W2^T bf16
  unsigned short* twt = (unsigned short*)alloc((size_t)16384 * 2);   // xform W bf16 frag

  // late-phase buffers aliased onto sedge_r (dead after k_sort_t)
  char* ap = (char*)sedge_r;
  auto alias = [&](size_t bytes) -> char* {
    char* p = ap;
    ap += (bytes + 255) & ~(size_t)255;
    return p;
  };
  float* recs_u = (float*)alias((size_t)NLV * BB * 32 * 4);
  float* recs_i = (float*)alias((size_t)NLV * BB * 32 * 4);
  float* att_u  = (float*)alias((size_t)BB * 96 * 4);
  float* att_i  = (float*)alias((size_t)BB * 96 * 4);
  unsigned short* n1b = (unsigned short*)alias((size_t)6 * BB * 32 * 2);
  unsigned short* n2b = (unsigned short*)alias((size_t)6 * BB * 32 * 2);

  // host-side: kc = jax.random.split(jax.random.key(42), 2)
  uint32_t a0 = 0, a1 = 2, b0 = 1, b1 = 3;
  tf_block(0u, 42u, a0, a1);
  tf_block(0u, 42u, b0, b1);
  uint32_t ku0 = a0, ku1 = b0;   // kc[0] -> u side
  uint32_t ki0 = a1, ki1 = b1;   // kc[1] -> i side

  k_init<<<10405, 256, 0, stream>>>(ego, E8a, uh_w, ud_w1, ud_w2,
                                    ih_w, id_w1, id_w2, gc_w, bi_w,
                                    s1t, s2t, s3t, twt, cursor, clbuf);
  k_scatter_t<<<(NNZE + EPB - 1) / EPB, 256, 0, stream>>>(adj_rows, adj_cols, adj_vals,
                                                          cursor, sedge_r);
  k_sort_t<<<NTILE, 256, 0, stream>>>(sedge_r, cursor, sedge, row_start);

  // layer 0: read E8a -> write E1 + E8b; layer 1: read E8b -> write E2 + E8a
  k_spmmt<<<9375, 256, 0, stream>>>(E8a, sedge, row_start,
                                    twt, gc_b, twt + 8192, bi_b,
                                    E1, (unsigned char*)E8b);
  k_spmmt<<<9375, 256, 0, stream>>>(E8b, sedge, row_start,
                                    twt + 4096, gc_b + 64, twt + 12288, bi_b + 64,
                                    E2, (unsigned char*)E8a);

  dim3 ge(128, 3, 2);
  k_encoder6<<<ge, 256, 0, stream>>>(ego, E1, E2, user_id, item_id,
                                     s1t, s2t, s3t,
                                     uh_b, ud_b1, ud_b2, ih_b, id_b1, id_b2,
                                     recs_u, recs_i);

  dim3 ga(512, 2);
  k_attnz<<<ga, 256, 0, stream>>>(recs_u, recs_i, q_w, q_b, k_w, k_b, v_w, v_b,
                                  ku0, ku1, ki0, ki1,
                                  att_u, att_i, n1b, n2b, posdot);

  k_ttl<<<384, 256, 0, stream>>>(n1b, n2b, posdot, clbuf, outp);

  k_head<<<1024, 256, 0, stream>>>(att_u, att_i, skills, dg_w1, dg_b1, dg_w2, dg_b2,
                                   pr_w, pr_b, outp);
}

// Round 13
// 497.531 us; speedup vs baseline: 1.0336x; 1.0336x over previous
//
#include <hip/hip_runtime.h>
#include <stdint.h>
#include <math.h>

#define USER_N 100000
#define NODE_N 150000
#define DD 64
#define NNZE 2400000
#define BB 4096
#define NLV 3
#define LF 32
#define HALF_SZ 196608u  /* (3*4096*32)/2 */
#define NTILE 586        /* ceil(150000/256) */
#define NSUB 8           /* per-tile sub-segments, one per physical XCD */
#define SCAP 1024        /* capacity per (tile,xcd) segment; mean 512 */
#define EPB 4096         /* edges per scatter block */
#define LCAP 5120        /* LDS staging cap per tile (mean 4096, sigma 64) */

typedef __attribute__((ext_vector_type(8))) short bf16x8;
typedef __attribute__((ext_vector_type(4))) float f32x4;
typedef __attribute__((ext_vector_type(2))) float f32x2;

// HW_REG_XCC_ID: id=20, offset=0, width=32 -> imm = 20 | (31<<11)
#define XCC_ID_IMM 63508

// ---------------- threefry2x32 (JAX original mode) ----------------
__host__ __device__ inline void tf_block(uint32_t k0, uint32_t k1, uint32_t& x0, uint32_t& x1) {
  uint32_t ks[3] = {k0, k1, k0 ^ k1 ^ 0x1BD11BDAu};
  x0 += ks[0]; x1 += ks[1];
  const int R0[4] = {13, 15, 26, 6};
  const int R1[4] = {17, 29, 16, 24};
#pragma unroll
  for (int i = 0; i < 5; ++i) {
    const int* R = (i & 1) ? R1 : R0;
#pragma unroll
    for (int j = 0; j < 4; ++j) {
      x0 += x1;
      x1 = (x1 << R[j]) | (x1 >> (32 - R[j]));
      x1 ^= x0;
    }
    x0 += ks[(i + 1) % 3];
    x1 += ks[(i + 2) % 3] + (uint32_t)(i + 1);
  }
}

__device__ inline float tf_uniform(uint32_t ka, uint32_t kb, uint32_t m) {
  uint32_t x0, x1;
  bool first = m < HALF_SZ;
  if (first) { x0 = m; x1 = m + HALF_SZ; } else { x0 = m - HALF_SZ; x1 = m; }
  tf_block(ka, kb, x0, x1);
  uint32_t bits = first ? x0 : x1;
  return __uint_as_float((bits >> 9) | 0x3f800000u) - 1.0f;
}

// bf16 round-to-nearest-even
__device__ inline unsigned short f2bf(float x) {
  uint32_t b = __float_as_uint(x);
  return (unsigned short)((b + 0x7FFFu + ((b >> 16) & 1u)) >> 16);
}

__device__ inline float b2f(unsigned short u) {
  return __uint_as_float(((uint32_t)u) << 16);
}

// fp8 e4m3 (HW cvt, OCP on gfx950): one byte from a float
__device__ inline unsigned char f2fp8(float x) {
  return (unsigned char)(__builtin_amdgcn_cvt_pk_fp8_f32(x, x, 0, false) & 0xFF);
}

// decode 4 packed e4m3 bytes -> 4 floats, then acc += v * row4
__device__ inline void fp8_fma(float4& acc, uint2 rec, uint32_t wrd) {
  float vv = __uint_as_float(rec.y);
  f32x2 lo = __builtin_amdgcn_cvt_pk_f32_fp8((int)wrd, false);
  f32x2 hi = __builtin_amdgcn_cvt_pk_f32_fp8((int)wrd, true);
  acc.x = fmaf(vv, lo.x, acc.x);
  acc.y = fmaf(vv, lo.y, acc.y);
  acc.z = fmaf(vv, hi.x, acc.z);
  acc.w = fmaf(vv, hi.y, acc.w);
}

// ---------------- kernels ----------------
// init (r21): fp8-mirror init (blocks < 9375) + encoder weight prep + transform
// weight prep (9375..10111) + cursor/cl zeroing (10111..10405).
// twt layout (per matrix, per layer): elem e -> j=e&7, quad=(e>>3)&3, h=(e>>5)&1,
// n=(e>>6)&15, c=e>>10; src k = h*32+quad*8+j; val = W[l*4096 + k*64 + c*16 + n].
__global__ __launch_bounds__(256) void k_init(
    const float* __restrict__ ego, uint32_t* __restrict__ E8,
    const float* __restrict__ uh_w, const float* __restrict__ ud_w1,
    const float* __restrict__ ud_w2, const float* __restrict__ ih_w,
    const float* __restrict__ id_w1, const float* __restrict__ id_w2,
    const float* __restrict__ gc_w, const float* __restrict__ bi_w,
    unsigned short* __restrict__ s1t, unsigned short* __restrict__ s2t,
    unsigned short* __restrict__ s3t, unsigned short* __restrict__ twt,
    int* __restrict__ cursor, float* __restrict__ clbuf) {
  if (blockIdx.x >= 10111) {
    int i = (blockIdx.x - 10111) * 256 + threadIdx.x;
    if (i < NTILE * NSUB * 16) cursor[i] = 0;
    if (i == 0) { clbuf[0] = 0.f; ((int*)clbuf)[1] = 0; }
    return;
  }
  if (blockIdx.x < 9375) {
    int i = blockIdx.x * 256 + threadIdx.x;  // float4 index
    float4 v = ((const float4*)ego)[i];
    int w01 = __builtin_amdgcn_cvt_pk_fp8_f32(v.x, v.y, 0, false);
    int w = __builtin_amdgcn_cvt_pk_fp8_f32(v.z, v.w, w01, true);
    E8[i] = (uint32_t)w;
    return;
  }
  int i = (blockIdx.x - 9375) * 256 + threadIdx.x;
  if (i < 24576) {                     // s1t[sl][e<64][d<64]
    int sl = i >> 12, r = i & 4095, e = r >> 6, d = r & 63;
    const float* src = (sl >= 3 ? ih_w : uh_w);
    int l = sl % 3;
    s1t[i] = f2bf(src[l * 4096 + d * 64 + e]);
  } else if (i < 24576 + 98304) {      // s2t[sl][e<256][d<64]
    int j = i - 24576;
    int sl = j >> 14, r = j & 16383, e = r >> 6, d = r & 63;
    const float* src = (sl >= 3 ? id_w1 : ud_w1);
    int l = sl % 3;
    s2t[j] = f2bf(src[l * 16384 + d * 256 + e]);
  } else if (i < 172032) {             // s3t[sl][e<32][d<256]
    int j = i - 24576 - 98304;
    int sl = j >> 13, r = j & 8191, e = r >> 8, d = r & 255;
    const float* src = (sl >= 3 ? id_w2 : ud_w2);
    int l = sl % 3;
    s3t[j] = f2bf(src[l * 8192 + d * 32 + e]);
  } else if (i < 172032 + 16384) {     // twt[m<2][l<2][e<4096]
    int j = i - 172032;
    int m = j >> 13;
    int rest = j & 8191;
    int l = rest >> 12;
    int e = rest & 4095;
    int jj = e & 7, quad = (e >> 3) & 3, h = (e >> 5) & 1;
    int n = (e >> 6) & 15, c = e >> 10;
    int k = h * 32 + quad * 8 + jj;
    const float* src = m ? bi_w : gc_w;
    twt[j] = f2bf(src[l * 4096 + k * 64 + c * 16 + n]);
  }
}

// Scatter v2 (r18): in-block counting sort over 586 tiles + LDS-staged
// writeout (bin-grouped bursts instead of 2.4M scattered 8B writes).
__global__ __launch_bounds__(256) void k_scatter_t(const int* __restrict__ rows,
                                                   const int* __restrict__ cols,
                                                   const float* __restrict__ vals,
                                                   int* __restrict__ cursor,
                                                   uint2* __restrict__ sedge_r) {
  __shared__ int cnt[NTILE];
  __shared__ int binbase[NTILE];
  __shared__ int gbase[NTILE];
  __shared__ int partial[256];
  __shared__ uint2 staged[EPB];            // 32KB
  __shared__ unsigned short tileof[EPB];   // 8KB
  int t = threadIdx.x;
  for (int i = t; i < NTILE; i += 256) cnt[i] = 0;
  __syncthreads();
  int ebase = blockIdx.x * EPB;
  int r[16], rk[16];
#pragma unroll
  for (int j = 0; j < 16; ++j) {
    int e = ebase + j * 256 + t;
    r[j] = (e < NNZE) ? rows[e] : -1;
    rk[j] = (r[j] >= 0) ? atomicAdd(&cnt[r[j] >> 8], 1) : 0;
  }
  __syncthreads();
  // scan over 586 bins: thread t owns bins [3t, 3t+own)
  int b0 = t * 3;
  int own = (b0 < NTILE) ? ((NTILE - b0 < 3) ? (NTILE - b0) : 3) : 0;
  int s0 = 0;
  for (int k = 0; k < own; ++k) s0 += cnt[b0 + k];
  partial[t] = s0;
  __syncthreads();
  for (int off = 1; off < 256; off <<= 1) {
    int add = (t >= off) ? partial[t - off] : 0;
    __syncthreads();
    partial[t] += add;
    __syncthreads();
  }
  int excl = partial[t] - s0;
  unsigned myx = __builtin_amdgcn_s_getreg(XCC_ID_IMM) & (NSUB - 1);
  {
    int run = excl;
    for (int k = 0; k < own; ++k) {
      int b = b0 + k;
      int c = cnt[b];
      binbase[b] = run;
      gbase[b] = c ? atomicAdd(&cursor[(b * NSUB + (int)myx) * 16], c) : 0;
      run += c;
    }
  }
  __syncthreads();
  // stage records bin-grouped
#pragma unroll
  for (int j = 0; j < 16; ++j) {
    if (r[j] < 0) continue;
    int e = ebase + j * 256 + t;
    int tile = r[j] >> 8;
    int pos = binbase[tile] + rk[j];
    staged[pos] = make_uint2((uint32_t)cols[e] | ((uint32_t)(r[j] & 255) << 18),
                             __float_as_uint(vals[e]));
    tileof[pos] = (unsigned short)tile;
  }
  __syncthreads();
  // writeout: staged order is bin-grouped -> bursts per tile range
  int nrec = NNZE - ebase;
  if (nrec > EPB) nrec = EPB;
  for (int i = t; i < nrec; i += 256) {
    int tile = tileof[i];
    int q = i - binbase[tile];
    int p = gbase[tile] + q;
    uint2 rec = staged[i];
    if (p < SCAP) {
      sedge_r[(size_t)(tile * NSUB + (int)myx) * SCAP + p] = rec;
    } else {
#pragma unroll 1
      for (int att = 1; att < NSUB; ++att) {
        int seg = tile * NSUB + (int)((myx + att) & (NSUB - 1));
        int p2 = atomicAdd(&cursor[seg * 16], 1);
        if (p2 < SCAP) { sedge_r[(size_t)seg * SCAP + p2] = rec; break; }
      }
    }
  }
}

// per-tile 256-bin counting sort (r16): folded scan + LDS-staged coalesced
// writeout.
__global__ __launch_bounds__(256) void k_sort_t(const uint2* __restrict__ sedge_r,
                                                const int* __restrict__ cursor,
                                                uint2* __restrict__ sedge,
                                                int* __restrict__ row_start) {
  __shared__ int hist[256], buf[256], curs[256];
  __shared__ int obase_s;
  __shared__ uint2 staged[LCAP];   // 40KB
  int t = threadIdx.x;
  int tile = blockIdx.x;
  if (t == 0) obase_s = 0;
  hist[t] = 0;
  __syncthreads();
  // folded scan: obase = sum of totals over tiles < tile (L2-resident reads)
  int ob = 0;
  for (int i = t; i < tile * NSUB; i += 256) {
    int c = cursor[i * 16];
    ob += (c < SCAP) ? c : SCAP;
  }
  if (ob) atomicAdd(&obase_s, ob);
  // histogram over this tile's 8 segments
  int segcnt[NSUB];
#pragma unroll
  for (int x = 0; x < NSUB; ++x) {
    int c = cursor[(tile * NSUB + x) * 16];
    segcnt[x] = (c < SCAP) ? c : SCAP;
  }
#pragma unroll 1
  for (int x = 0; x < NSUB; ++x) {
    const uint2* sp = sedge_r + (size_t)(tile * NSUB + x) * SCAP;
    for (int i = t; i < segcnt[x]; i += 256)
      atomicAdd(&hist[sp[i].x >> 18], 1);
  }
  __syncthreads();
  int obase = obase_s;
  int v = hist[t];
  buf[t] = v;
  __syncthreads();
  for (int off = 1; off < 256; off <<= 1) {
    int add = (t >= off) ? buf[t - off] : 0;
    __syncthreads();
    buf[t] += add;
    __syncthreads();
  }
  int total = buf[255];
  int excl = buf[t] - v;
  curs[t] = excl;
  int row = tile * 256 + t;
  if (row < NODE_N) row_start[row] = obase + excl;
  if (tile == NTILE - 1 && t == 0) row_start[NODE_N] = NNZE;
  __syncthreads();
#pragma unroll 1
  for (int x = 0; x < NSUB; ++x) {
    const uint2* sp = sedge_r + (size_t)(tile * NSUB + x) * SCAP;
    for (int i = t; i < segcnt[x]; i += 256) {
      uint2 rec = sp[i];
      int rl = rec.x >> 18;
      int p = atomicAdd(&curs[rl], 1);
      uint2 outrec = make_uint2(rec.x & 0x3FFFFu, rec.y);
      if (p < LCAP) staged[p] = outrec;
      else sedge[obase + p] = outrec;   // 16-sigma fallback
    }
  }
  __syncthreads();
  int n = (total < LCAP) ? total : LCAP;
  for (int i = t; i < n; i += 256)
    sedge[obase + i] = staged[i];
}

// Fused SpMM+transform v3 (r23): bf16 Eout kept (r22: WRITE 46.9->28.1MB,
// absmax unchanged); weight PREFETCH REVERTED (r22 lesson: hoisting 16 VGPRs
// across phase 1 cost 78->68% occupancy and +9us -- worse than the ~600cy
// once-per-block load it saved). Weights load after the phase-1 barrier,
// exactly like the 98us r21 version.
__global__ __launch_bounds__(256) void k_spmmt(const uint32_t* __restrict__ E8in,
                                               const uint2* __restrict__ sedge,
                                               const int* __restrict__ row_start,
                                               const unsigned short* __restrict__ gwt,
                                               const float* __restrict__ gb,
                                               const unsigned short* __restrict__ bwt,
                                               const float* __restrict__ bb,
                                               unsigned short* __restrict__ Eout,
                                               unsigned char* __restrict__ E8out) {
  __shared__ unsigned short sS[16][72];   // side tile bf16 (pad 72)
  __shared__ unsigned short sP[16][72];   // E.side tile
  __shared__ float sqp[4][16];            // per-wave partial l2 sums
  int t = threadIdx.x;
  int wv = t >> 6, lane = t & 63;
  int i0 = blockIdx.x * 16;
  // ---- phase 1: spmm, wave wv handles rows i0+wv*4 .. +3 ----
  {
    int g = lane >> 4;
    int q = lane & 15;
#pragma unroll 1
    for (int rr = 0; rr < 4; ++rr) {
      int r = i0 + wv * 4 + rr;
      int rs = row_start[r], re = row_start[r + 1];
      float4 acc = make_float4(0.f, 0.f, 0.f, 0.f);
      int e = rs;
      for (; e + 16 <= re; e += 16) {
        uint2 e0 = sedge[e + g];
        uint2 e1 = sedge[e + 4 + g];
        uint2 e2 = sedge[e + 8 + g];
        uint2 e3 = sedge[e + 12 + g];
        uint32_t a0 = E8in[(size_t)e0.x * 16 + q];
        uint32_t a1 = E8in[(size_t)e1.x * 16 + q];
        uint32_t a2 = E8in[(size_t)e2.x * 16 + q];
        uint32_t a3 = E8in[(size_t)e3.x * 16 + q];
        fp8_fma(acc, e0, a0);
        fp8_fma(acc, e1, a1);
        fp8_fma(acc, e2, a2);
        fp8_fma(acc, e3, a3);
      }
      for (; e + 8 <= re; e += 8) {
        uint2 e0 = sedge[e + g];
        uint2 e1 = sedge[e + 4 + g];
        uint32_t a0 = E8in[(size_t)e0.x * 16 + q];
        uint32_t a1 = E8in[(size_t)e1.x * 16 + q];
        fp8_fma(acc, e0, a0);
        fp8_fma(acc, e1, a1);
      }
      for (; e + 4 <= re; e += 4) {
        uint2 e0 = sedge[e + g];
        uint32_t a0 = E8in[(size_t)e0.x * 16 + q];
        fp8_fma(acc, e0, a0);
      }
      for (; e < re; ++e) {
        if (g == (e & 3)) {
          uint2 e0 = sedge[e];
          uint32_t a0 = E8in[(size_t)e0.x * 16 + q];
          fp8_fma(acc, e0, a0);
        }
      }
#pragma unroll
      for (int off = 16; off <= 32; off <<= 1) {
        acc.x += __shfl_xor(acc.x, off, 64);
        acc.y += __shfl_xor(acc.y, off, 64);
        acc.z += __shfl_xor(acc.z, off, 64);
        acc.w += __shfl_xor(acc.w, off, 64);
      }
      if (g == 0) {
        uint32_t ew = E8in[(size_t)r * 16 + q];
        f32x2 elo = __builtin_amdgcn_cvt_pk_f32_fp8((int)ew, false);
        f32x2 ehi = __builtin_amdgcn_cvt_pk_f32_fp8((int)ew, true);
        int lr = wv * 4 + rr;
        ushort4 vs, vp;
        vs.x = f2bf(acc.x); vs.y = f2bf(acc.y);
        vs.z = f2bf(acc.z); vs.w = f2bf(acc.w);
        vp.x = f2bf(acc.x * elo.x); vp.y = f2bf(acc.y * elo.y);
        vp.z = f2bf(acc.z * ehi.x); vp.w = f2bf(acc.w * ehi.y);
        *(ushort4*)&sS[lr][q * 4] = vs;
        *(ushort4*)&sP[lr][q * 4] = vp;
      }
    }
  }
  __syncthreads();
  // ---- phase 2: transform; wave wv = output colblock c (weights loaded
  // HERE, post-barrier: once per block, no phase-1 VGPR pressure) ----
  int n = lane & 15, quad = lane >> 4;
  const f32x4 z = {0.f, 0.f, 0.f, 0.f};
  bf16x8 wg0 = *(const bf16x8*)&gwt[((size_t)(wv * 16 + n) * 2 + 0) * 32 + quad * 8];
  bf16x8 wg1 = *(const bf16x8*)&gwt[((size_t)(wv * 16 + n) * 2 + 1) * 32 + quad * 8];
  bf16x8 wb0 = *(const bf16x8*)&bwt[((size_t)(wv * 16 + n) * 2 + 0) * 32 + quad * 8];
  bf16x8 wb1 = *(const bf16x8*)&bwt[((size_t)(wv * 16 + n) * 2 + 1) * 32 + quad * 8];
  float gbl = gb[wv * 16 + n];
  float bbl = bb[wv * 16 + n];
  bf16x8 as0 = *(const bf16x8*)&sS[n][quad * 8];
  bf16x8 as1 = *(const bf16x8*)&sS[n][32 + quad * 8];
  bf16x8 ap0 = *(const bf16x8*)&sP[n][quad * 8];
  bf16x8 ap1 = *(const bf16x8*)&sP[n][32 + quad * 8];
  f32x4 ag = __builtin_amdgcn_mfma_f32_16x16x32_bf16(as0, wg0, z, 0, 0, 0);
  ag = __builtin_amdgcn_mfma_f32_16x16x32_bf16(as1, wg1, ag, 0, 0, 0);
  f32x4 ab = __builtin_amdgcn_mfma_f32_16x16x32_bf16(ap0, wb0, z, 0, 0, 0);
  ab = __builtin_amdgcn_mfma_f32_16x16x32_bf16(ap1, wb1, ab, 0, 0, 0);
  float v[4];
  float sq[4];
#pragma unroll
  for (int r = 0; r < 4; ++r) {
    float a1 = ag[r] + gbl;
    a1 = (a1 > 0.f) ? a1 : 0.01f * a1;
    float a2 = ab[r] + bbl;
    a2 = (a2 > 0.f) ? a2 : 0.01f * a2;
    float vv = a1 + a2;
    v[r] = vv;
    sq[r] = vv * vv;
  }
#pragma unroll
  for (int off = 1; off < 16; off <<= 1) {
    sq[0] += __shfl_xor(sq[0], off, 64);
    sq[1] += __shfl_xor(sq[1], off, 64);
    sq[2] += __shfl_xor(sq[2], off, 64);
    sq[3] += __shfl_xor(sq[3], off, 64);
  }
  if (n == 0) {
#pragma unroll
    for (int r = 0; r < 4; ++r) sqp[wv][quad * 4 + r] = sq[r];
  }
  __syncthreads();
#pragma unroll
  for (int r = 0; r < 4; ++r) {
    int row = quad * 4 + r;
    float tot = sqp[0][row] + sqp[1][row] + sqp[2][row] + sqp[3][row];
    float inv = 1.f / fmaxf(sqrtf(tot), 1e-12f);
    float vn = v[r] * inv;
    size_t o = (size_t)(i0 + row) * DD + wv * 16 + n;
    Eout[o] = f2bf(vn);
    E8out[o] = f2fp8(vn);
  }
}

// Encoder v7 (r22): E1/E2 consumed as bf16 (converted to fp32 before the sum;
// ego stays fp32). Otherwise identical to the verified v6.
__global__ __launch_bounds__(256) void k_encoder6(
    const float* __restrict__ ego, const unsigned short* __restrict__ E1,
    const unsigned short* __restrict__ E2, const int* __restrict__ uid,
    const int* __restrict__ iid,
    const unsigned short* __restrict__ s1t, const unsigned short* __restrict__ s2t,
    const unsigned short* __restrict__ s3t,
    const float* __restrict__ uh_b, const float* __restrict__ ud_b1,
    const float* __restrict__ ud_b2, const float* __restrict__ ih_b,
    const float* __restrict__ id_b1, const float* __restrict__ id_b2,
    float* __restrict__ recs_u, float* __restrict__ recs_i) {
  __shared__ unsigned short X[32][72];    // 4.6KB (pad 72: conflict-free)
  __shared__ unsigned short R1[32][64];   // 4KB
  __shared__ unsigned short T[32][256];   // 16KB
  int t = threadIdx.x;
  int w = t >> 6, lane = t & 63;
  int n = lane & 15, quad = lane >> 4;
  int trow = w & 1;      // which 16-row tile
  int cg = w >> 1;       // column-group half
  int r0 = blockIdx.x * 32;
  int l = blockIdx.y, side = blockIdx.z;
  int sl = side * 3 + l;
  const float* hb = side ? ih_b : uh_b;
  const float* bb1 = side ? id_b1 : ud_b1;
  const float* bb2 = side ? id_b2 : ud_b2;
  float* recs = side ? recs_i : recs_u;
  const f32x4 z = {0.f, 0.f, 0.f, 0.f};

  {  // gather 32 rows: X = bf16(ego + E1 + E2) at uid/iid rows (E1/E2 bf16)
    int row = t >> 3;
    int c0 = (t & 7) * 8;
    int node = side ? (USER_N + iid[r0 + row]) : uid[r0 + row];
    const float* pe = ego + (size_t)node * 64 + c0;
    bf16x8 v1 = *(const bf16x8*)(E1 + (size_t)node * 64 + c0);
    bf16x8 v2 = *(const bf16x8*)(E2 + (size_t)node * 64 + c0);
#pragma unroll
    for (int j = 0; j < 8; ++j)
      X[row][c0 + j] = f2bf(pe[j] + b2f((unsigned short)v1[j]) +
                            b2f((unsigned short)v2[j]));
  }
  __syncthreads();

  {  // stage1: R1 = tanh(X @ W0 + b0). 16x64 out per tile; wave: 2 colblocks.
    bf16x8 a0 = *(const bf16x8*)&X[trow * 16 + n][quad * 8];
    bf16x8 a1 = *(const bf16x8*)&X[trow * 16 + n][32 + quad * 8];
    const unsigned short* Wt = s1t + (size_t)sl * 4096;  // [e=64][d=64]
#pragma unroll
    for (int cc = 0; cc < 2; ++cc) {
      int cb = cg * 2 + cc;
      bf16x8 wb0 = *(const bf16x8*)&Wt[(size_t)(cb * 16 + n) * 64 + quad * 8];
      bf16x8 wb1 = *(const bf16x8*)&Wt[(size_t)(cb * 16 + n) * 64 + 32 + quad * 8];
      f32x4 acc = __builtin_amdgcn_mfma_f32_16x16x32_bf16(a0, wb0, z, 0, 0, 0);
      acc = __builtin_amdgcn_mfma_f32_16x16x32_bf16(a1, wb1, acc, 0, 0, 0);
      float bias = hb[l * 64 + cb * 16 + n];
#pragma unroll
      for (int r = 0; r < 4; ++r)
        R1[trow * 16 + quad * 4 + r][cb * 16 + n] = f2bf(tanhf(acc[r] + bias));
    }
  }
  __syncthreads();

  {  // stage2: T = tanh(R1 @ W1 + b1). 16x256 per tile; wave: 8 colblocks.
    bf16x8 a0 = *(const bf16x8*)&R1[trow * 16 + n][quad * 8];
    bf16x8 a1 = *(const bf16x8*)&R1[trow * 16 + n][32 + quad * 8];
    const unsigned short* Wt = s2t + (size_t)sl * 16384;  // [e=256][d=64]
#pragma unroll
    for (int cc = 0; cc < 8; ++cc) {
      int cb = cg * 8 + cc;
      bf16x8 wb0 = *(const bf16x8*)&Wt[(size_t)(cb * 16 + n) * 64 + quad * 8];
      bf16x8 wb1 = *(const bf16x8*)&Wt[(size_t)(cb * 16 + n) * 64 + 32 + quad * 8];
      f32x4 acc = __builtin_amdgcn_mfma_f32_16x16x32_bf16(a0, wb0, z, 0, 0, 0);
      acc = __builtin_amdgcn_mfma_f32_16x16x32_bf16(a1, wb1, acc, 0, 0, 0);
      float bias = bb1[l * 256 + cb * 16 + n];
#pragma unroll
      for (int r = 0; r < 4; ++r)
        T[trow * 16 + quad * 4 + r][cb * 16 + n] = f2bf(tanhf(acc[r] + bias));
    }
  }
  __syncthreads();

  {  // stage3: recs = T @ W2 + b2. K=256 chained; wave: 1 colblock (cg).
    const unsigned short* Wt = s3t + (size_t)sl * 8192;  // [e=32][d=256]
    f32x4 acc = z;
#pragma unroll
    for (int h = 0; h < 8; ++h) {
      bf16x8 a = *(const bf16x8*)&T[trow * 16 + n][h * 32 + quad * 8];
      bf16x8 b = *(const bf16x8*)&Wt[(size_t)(cg * 16 + n) * 256 + h * 32 + quad * 8];
      acc = __builtin_amdgcn_mfma_f32_16x16x32_bf16(a, b, acc, 0, 0, 0);
    }
    float bias = bb2[l * 32 + cg * 16 + n];
#pragma unroll
    for (int r = 0; r < 4; ++r)
      recs[((size_t)l * BB + (r0 + trow * 16 + quad * 4 + r)) * 32 + cg * 16 + n] =
          acc[r] + bias;
  }
}

// attn+noise fused (r19): noise consumes exactly the att values attn computes
// per-lane (s<->l, d<->k). Threefry mapping identical to the original k_noise.
__global__ __launch_bounds__(256) void k_attnz(const float* __restrict__ recs_u,
                                               const float* __restrict__ recs_i,
                                               const float* __restrict__ qw, const float* __restrict__ qb,
                                               const float* __restrict__ kw, const float* __restrict__ kb,
                                               const float* __restrict__ vw, const float* __restrict__ vb,
                                               uint32_t ku0, uint32_t ku1, uint32_t ki0, uint32_t ki1,
                                               float* __restrict__ att_u, float* __restrict__ att_i,
                                               unsigned short* __restrict__ n1b,
                                               unsigned short* __restrict__ n2b,
                                               float* __restrict__ posdot) {
  int side = blockIdx.y;
  const float* recs = side ? recs_i : recs_u;
  float* att = side ? att_i : att_u;
  uint32_t ka = side ? ki0 : ku0;
  uint32_t kb2 = side ? ki1 : ku1;
  int t = threadIdx.x;
  int b = blockIdx.x * 8 + (t >> 5);
  int d = t & 31;
  float x0 = recs[((size_t)0 * BB + b) * 32 + d];
  float x1 = recs[((size_t)1 * BB + b) * 32 + d];
  float x2 = recs[((size_t)2 * BB + b) * 32 + d];
  float q0 = qb[d], q1 = q0, q2 = q0;
  float c0 = kb[d], c1 = c0, c2 = c0;
  float v0 = vb[d], v1 = v0, v2 = v0;
#pragma unroll 4
  for (int kk = 0; kk < 32; ++kk) {
    float xa = __shfl(x0, kk, 32);
    float xb = __shfl(x1, kk, 32);
    float xc = __shfl(x2, kk, 32);
    float wq = qw[kk * 32 + d], wk = kw[kk * 32 + d], wv = vw[kk * 32 + d];
    q0 += xa * wq; q1 += xb * wq; q2 += xc * wq;
    c0 += xa * wk; c1 += xb * wk; c2 += xc * wk;
    v0 += xa * wv; v1 += xb * wv; v2 += xc * wv;
  }
  float qs[3] = {q0, q1, q2}, ks[3] = {c0, c1, c2}, vs[3] = {v0, v1, v2};
  float sc[3][3];
#pragma unroll
  for (int s = 0; s < 3; ++s)
#pragma unroll
    for (int u = 0; u < 3; ++u) {
      float p = qs[s] * ks[u];
#pragma unroll
      for (int off = 16; off; off >>= 1) p += __shfl_xor(p, off, 32);
      sc[s][u] = p * 0.17677669529663687f;  // 1/sqrt(32)
    }
#pragma unroll
  for (int s = 0; s < 3; ++s) {
    float m = fmaxf(sc[s][0], fmaxf(sc[s][1], sc[s][2]));
    float e0 = __expf(sc[s][0] - m), e1 = __expf(sc[s][1] - m), e2 = __expf(sc[s][2] - m);
    float inv = 1.f / (e0 + e1 + e2);
    float r = (e0 * vs[0] + e1 * vs[1] + e2 * vs[2]) * inv;
    att[(size_t)b * 96 + s * 32 + d] = r;
    // ---- noise (was k_noise) ----
    float ss = r * r;
#pragma unroll
    for (int off = 16; off; off >>= 1) ss += __shfl_xor(ss, off, 32);
    float nv1 = r / fmaxf(sqrtf(ss), 1e-12f);
    uint32_t mm = ((uint32_t)(s * BB + b)) * 32u + (uint32_t)d;
    float u = tf_uniform(ka, kb2, mm);
    float us = u * u;
#pragma unroll
    for (int off = 16; off; off >>= 1) us += __shfl_xor(us, off, 32);
    float un = u / fmaxf(sqrtf(us), 1e-12f);
    float sgn = (r > 0.f) ? 1.f : ((r < 0.f) ? -1.f : 0.f);
    float rn = r + sgn * un * 0.1f;
    float s2 = rn * rn;
#pragma unroll
    for (int off = 16; off; off >>= 1) s2 += __shfl_xor(s2, off, 32);
    float nv2 = rn / fmaxf(sqrtf(s2), 1e-12f);
    float pd = nv1 * nv2;
#pragma unroll
    for (int off = 16; off; off >>= 1) pd += __shfl_xor(pd, off, 32);
    int g = side * (NLV * BB) + s * BB + b;
    size_t o = (size_t)g * 32 + d;
    n1b[o] = f2bf(nv1);
    n2b[o] = f2bf(nv2);
    if (d == 0) posdot[g] = pd;
  }
}

// ttl via MFMA + clred FOLDED IN (r19): block-reduce log(ttl)-5*posdot, one
// atomicAdd per block; last block (counter) writes the final cl output.
__global__ __launch_bounds__(256) void k_ttl(const unsigned short* __restrict__ n1b,
                                             const unsigned short* __restrict__ n2b,
                                             const float* __restrict__ posdot,
                                             float* __restrict__ clbuf,
                                             float* __restrict__ outp) {
  __shared__ float ws[4];
  int t = threadIdx.x;
  int wv = t >> 6, lane = t & 63;
  int sl = blockIdx.x >> 6;            // 6 slices
  int istripe = blockIdx.x & 63;       // 64 stripes of 64 rows
  int i0 = istripe * 64 + wv * 16;
  const unsigned short* ab = n1b + (size_t)sl * BB * 32;
  const unsigned short* bb = n2b + (size_t)sl * BB * 32;
  int m = lane & 15, quad = lane >> 4;
  bf16x8 afrag = *(const bf16x8*)&ab[(size_t)(i0 + m) * 32 + quad * 8];
  float r0a = 0.f, r1a = 0.f, r2a = 0.f, r3a = 0.f;
  f32x4 z = {0.f, 0.f, 0.f, 0.f};
  for (int jt = 0; jt < 256; jt += 4) {
    bf16x8 b0 = *(const bf16x8*)&bb[((size_t)((jt + 0) * 16 + m)) * 32 + quad * 8];
    bf16x8 b1 = *(const bf16x8*)&bb[((size_t)((jt + 1) * 16 + m)) * 32 + quad * 8];
    bf16x8 b2 = *(const bf16x8*)&bb[((size_t)((jt + 2) * 16 + m)) * 32 + quad * 8];
    bf16x8 b3 = *(const bf16x8*)&bb[((size_t)((jt + 3) * 16 + m)) * 32 + quad * 8];
    f32x4 s0 = __builtin_amdgcn_mfma_f32_16x16x32_bf16(afrag, b0, z, 0, 0, 0);
    f32x4 s1 = __builtin_amdgcn_mfma_f32_16x16x32_bf16(afrag, b1, z, 0, 0, 0);
    f32x4 s2 = __builtin_amdgcn_mfma_f32_16x16x32_bf16(afrag, b2, z, 0, 0, 0);
    f32x4 s3 = __builtin_amdgcn_mfma_f32_16x16x32_bf16(afrag, b3, z, 0, 0, 0);
    r0a += __expf(s0.x * 5.f) + __expf(s1.x * 5.f) + __expf(s2.x * 5.f) + __expf(s3.x * 5.f);
    r1a += __expf(s0.y * 5.f) + __expf(s1.y * 5.f) + __expf(s2.y * 5.f) + __expf(s3.y * 5.f);
    r2a += __expf(s0.z * 5.f) + __expf(s1.z * 5.f) + __expf(s2.z * 5.f) + __expf(s3.z * 5.f);
    r3a += __expf(s0.w * 5.f) + __expf(s1.w * 5.f) + __expf(s2.w * 5.f) + __expf(s3.w * 5.f);
  }
#pragma unroll
  for (int off = 1; off < 16; off <<= 1) {
    r0a += __shfl_xor(r0a, off, 64);
    r1a += __shfl_xor(r1a, off, 64);
    r2a += __shfl_xor(r2a, off, 64);
    r3a += __shfl_xor(r3a, off, 64);
  }
  float part = 0.f;
  if (m == 0) {
    int rbase = sl * BB + i0 + quad * 4;
    part = (logf(r0a) - posdot[rbase + 0] * 5.0f)
         + (logf(r1a) - posdot[rbase + 1] * 5.0f)
         + (logf(r2a) - posdot[rbase + 2] * 5.0f)
         + (logf(r3a) - posdot[rbase + 3] * 5.0f);
  }
#pragma unroll
  for (int off = 1; off < 64; off <<= 1)
    part += __shfl_xor(part, off, 64);
  if (lane == 0) ws[wv] = part;
  __syncthreads();
  if (t == 0) {
    float blk = ws[0] + ws[1] + ws[2] + ws[3];
    atomicAdd(&clbuf[0], blk);
    __threadfence();
    int done = atomicAdd((int*)&clbuf[1], 1);
    if (done == 383) {
      float total = atomicAdd(&clbuf[0], 0.0f);
      outp[2 * BB] = total * (1.f / 12288.f);
    }
  }
}

__global__ __launch_bounds__(256) void k_head(const float* __restrict__ att_u,
                                              const float* __restrict__ att_i,
                                              const float* __restrict__ skills,
                                              const float* __restrict__ w1, const float* __restrict__ b1,
                                              const float* __restrict__ w2, const float* __restrict__ b2,
                                              const float* __restrict__ pw, const float* __restrict__ pb,
                                              float* __restrict__ outp) {
  __shared__ float diag[4][96], t1[4][64];
  int t = threadIdx.x;
  int w = t >> 6, lane = t & 63;
  int b = blockIdx.x * 4 + w;
  for (int j = lane; j < 96; j += 64) {
    float su = 1.f / (1.f + __expf(-att_u[(size_t)b * 96 + j]));
    float si = 1.f / (1.f + __expf(-att_i[(size_t)b * 96 + j]));
    diag[w][j] = (su - si) * skills[(size_t)b * 96 + j];
  }
  __syncthreads();
  float a = b1[lane];
#pragma unroll 8
  for (int j = 0; j < 96; ++j) a += diag[w][j] * w1[j * 64 + lane];
  t1[w][lane] = tanhf(a);
  __syncthreads();
  float h = b2[lane];
#pragma unroll 8
  for (int kk = 0; kk < 64; ++kk) h += t1[w][kk] * w2[kk * 64 + lane];
  float p0 = h * pw[lane * 2 + 0];
  float p1 = h * pw[lane * 2 + 1];
#pragma unroll
  for (int off = 32; off; off >>= 1) {
    p0 += __shfl_xor(p0, off, 64);
    p1 += __shfl_xor(p1, off, 64);
  }
  if (lane == 0) {
    float l0 = p0 + pb[0], l1 = p1 + pb[1];
    float m = fmaxf(l0, l1);
    float e0 = __expf(l0 - m), e1 = __expf(l1 - m);
    float inv = 1.f / (e0 + e1);
    outp[(size_t)b * 2 + 0] = e0 * inv;
    outp[(size_t)b * 2 + 1] = e1 * inv;
  }
}

// ---------------- launcher ----------------
extern "C" void kernel_launch(void* const* d_in, const int* in_sizes, int n_in,
                              void* d_out, int out_size, void* d_ws, size_t ws_size,
                              hipStream_t stream) {
  const float* ego    = (const float*)d_in[0];
  const float* gc_w   = (const float*)d_in[1];
  const float* gc_b   = (const float*)d_in[2];
  const float* bi_w   = (const float*)d_in[3];
  const float* bi_b   = (const float*)d_in[4];
  const float* uh_w   = (const float*)d_in[5];
  const float* uh_b   = (const float*)d_in[6];
  const float* ih_w   = (const float*)d_in[7];
  const float* ih_b   = (const float*)d_in[8];
  const float* ud_w1  = (const float*)d_in[9];
  const float* ud_b1  = (const float*)d_in[10];
  const float* ud_w2  = (const float*)d_in[11];
  const float* ud_b2  = (const float*)d_in[12];
  const float* id_w1  = (const float*)d_in[13];
  const float* id_b1  = (const float*)d_in[14];
  const float* id_w2  = (const float*)d_in[15];
  const float* id_b2  = (const float*)d_in[16];
  const float* q_w    = (const float*)d_in[17];
  const float* q_b    = (const float*)d_in[18];
  const float* k_w    = (const float*)d_in[19];
  const float* k_b    = (const float*)d_in[20];
  const float* v_w    = (const float*)d_in[21];
  const float* v_b    = (const float*)d_in[22];
  const float* dg_w1  = (const float*)d_in[23];
  const float* dg_b1  = (const float*)d_in[24];
  const float* dg_w2  = (const float*)d_in[25];
  const float* dg_b2  = (const float*)d_in[26];
  const float* pr_w   = (const float*)d_in[27];
  const float* pr_b   = (const float*)d_in[28];
  const float* adj_vals = (const float*)d_in[29];
  const float* skills = (const float*)d_in[30];
  const int* user_id  = (const int*)d_in[31];
  const int* item_id  = (const int*)d_in[32];
  const int* adj_rows = (const int*)d_in[33];
  const int* adj_cols = (const int*)d_in[34];
  float* outp = (float*)d_out;

  char* w = (char*)d_ws;
  auto alloc = [&](size_t bytes) -> char* {
    char* p = w;
    w += (bytes + 255) & ~(size_t)255;
    return p;
  };
  unsigned short* E1 = (unsigned short*)alloc((size_t)NODE_N * DD * 2);  // bf16
  unsigned short* E2 = (unsigned short*)alloc((size_t)NODE_N * DD * 2);  // bf16
  uint32_t* E8a = (uint32_t*)alloc((size_t)NODE_N * DD);   // fp8 mirror A, 9.6MB
  uint32_t* E8b = (uint32_t*)alloc((size_t)NODE_N * DD);   // fp8 mirror B, 9.6MB
  uint2* sedge_r= (uint2*)alloc((size_t)NTILE * NSUB * SCAP * 8);  // dead after sort
  uint2* sedge  = (uint2*)alloc((size_t)NNZE * 8);   // row-sorted CSR
  int*   cursor = (int*)  alloc((size_t)NTILE * NSUB * 16 * 4);
  int*   row_start = (int*)alloc((size_t)(NODE_N + 1) * 4);
  float* posdot = (float*)alloc((size_t)6 * BB * 4);
  float* clbuf  = (float*)alloc(256);                  // [0]=acc, [1]=cnt
  unsigned short* s1t = (unsigned short*)alloc((size_t)24576 * 2);   // enc W0^T bf16
  unsigned short* s2t = (unsigned short*)alloc((size_t)98304 * 2);   // enc W1^T bf16
  unsigned short* s3t = (unsigned short*)alloc((size_t)49152 * 2);   // enc W2^T bf16
  unsigned short* twt = (unsigned short*)alloc((size_t)16384 * 2);   // xform W bf16 frag

  // late-phase buffers aliased onto sedge_r (dead after k_sort_t)
  char* ap = (char*)sedge_r;
  auto alias = [&](size_t bytes) -> char* {
    char* p = ap;
    ap += (bytes + 255) & ~(size_t)255;
    return p;
  };
  float* recs_u = (float*)alias((size_t)NLV * BB * 32 * 4);
  float* recs_i = (float*)alias((size_t)NLV * BB * 32 * 4);
  float* att_u  = (float*)alias((size_t)BB * 96 * 4);
  float* att_i  = (float*)alias((size_t)BB * 96 * 4);
  unsigned short* n1b = (unsigned short*)alias((size_t)6 * BB * 32 * 2);
  unsigned short* n2b = (unsigned short*)alias((size_t)6 * BB * 32 * 2);

  // host-side: kc = jax.random.split(jax.random.key(42), 2)
  uint32_t a0 = 0, a1 = 2, b0 = 1, b1 = 3;
  tf_block(0u, 42u, a0, a1);
  tf_block(0u, 42u, b0, b1);
  uint32_t ku0 = a0, ku1 = b0;   // kc[0] -> u side
  uint32_t ki0 = a1, ki1 = b1;   // kc[1] -> i side

  k_init<<<10405, 256, 0, stream>>>(ego, E8a, uh_w, ud_w1, ud_w2,
                                    ih_w, id_w1, id_w2, gc_w, bi_w,
                                    s1t, s2t, s3t, twt, cursor, clbuf);
  k_scatter_t<<<(NNZE + EPB - 1) / EPB, 256, 0, stream>>>(adj_rows, adj_cols, adj_vals,
                                                          cursor, sedge_r);
  k_sort_t<<<NTILE, 256, 0, stream>>>(sedge_r, cursor, sedge, row_start);

  // layer 0: read E8a -> write E1 + E8b; layer 1: read E8b -> write E2 + E8a
  k_spmmt<<<9375, 256, 0, stream>>>(E8a, sedge, row_start,
                                    twt, gc_b, twt + 8192, bi_b,
                                    E1, (unsigned char*)E8b);
  k_spmmt<<<9375, 256, 0, stream>>>(E8b, sedge, row_start,
                                    twt + 4096, gc_b + 64, twt + 12288, bi_b + 64,
                                    E2, (unsigned char*)E8a);

  dim3 ge(128, 3, 2);
  k_encoder6<<<ge, 256, 0, stream>>>(ego, E1, E2, user_id, item_id,
                                     s1t, s2t, s3t,
                                     uh_b, ud_b1, ud_b2, ih_b, id_b1, id_b2,
                                     recs_u, recs_i);

  dim3 ga(512, 2);
  k_attnz<<<ga, 256, 0, stream>>>(recs_u, recs_i, q_w, q_b, k_w, k_b, v_w, v_b,
                                  ku0, ku1, ki0, ki1,
                                  att_u, att_i, n1b, n2b, posdot);

  k_ttl<<<384, 256, 0, stream>>>(n1b, n2b, posdot, clbuf, outp);

  k_head<<<1024, 256, 0, stream>>>(att_u, att_i, skills, dg_w1, dg_b1, dg_w2, dg_b2,
                                   pr_w, pr_b, outp);
}